// Round 4
// baseline (424.372 us; speedup 1.0000x reference)
//
#include <hip/hip_runtime.h>

#define NN 50000
#define NE 800000
#define D 64
#define BN_SH 8
#define BNODES 256
#define NB ((NN + BNODES - 1) / BNODES)     // 196 buckets
#define EPB 4096
#define NWB ((NE + EPB - 1) / EPB)          // 196 bin_write blocks

// ---- workspace layout ----
constexpr size_t alignup(size_t x) { return (x + 1023) & ~size_t(1023); }
constexpr size_t OFF_AGG  = 0;                                        // NN*D f32 = 12.8 MB
constexpr size_t OFF_EM   = alignup(OFF_AGG + (size_t)NN * D * 4);    // NE*8 = 6.4 MB
constexpr size_t OFF_BC   = alignup(OFF_EM + (size_t)NE * 8);         // NB i32
constexpr size_t OFF_BASE = alignup(OFF_BC + NB * 4);                 // NB+1 i32
constexpr size_t OFF_CUR  = alignup(OFF_BASE + (NB + 1) * 4);         // NB i32

// K0: zero bucket counters
__global__ __launch_bounds__(256) void gc_zero(int* bc) {
    int t = threadIdx.x;
    if (t < NB) bc[t] = 0;
}

// K1: bucket histogram (196 counters, LDS-staged)
__global__ __launch_bounds__(256) void bin_count(const int* __restrict__ dst, int* bc) {
    __shared__ int h[NB];
    for (int i = threadIdx.x; i < NB; i += 256) h[i] = 0;
    __syncthreads();
    for (int e = blockIdx.x * 256 + threadIdx.x; e < NE; e += gridDim.x * 256)
        atomicAdd(&h[dst[e] >> BN_SH], 1);
    __syncthreads();
    for (int i = threadIdx.x; i < NB; i += 256) {
        int c = h[i];
        if (c) atomicAdd(&bc[i], c);
    }
}

// K2: exclusive scan of 196 bucket counts (single block); init cursors
__global__ __launch_bounds__(256) void bucket_scan(const int* __restrict__ bc,
                                                   int* base, int* cur) {
    __shared__ int sh[256];
    int t = threadIdx.x;
    int v = (t < NB) ? bc[t] : 0;
    sh[t] = v;
    __syncthreads();
    for (int o = 1; o < 256; o <<= 1) {
        int x = (t >= o) ? sh[t - o] : 0;
        __syncthreads();
        sh[t] += x;
        __syncthreads();
    }
    if (t < NB) { int ex = sh[t] - v; base[t] = ex; cur[t] = ex; }
    if (t == 0) base[NB] = NE;
}

// K3: binned edge write with per-block bulk reservation.
// rec = { src | dst_local<<16 , bits(ew) }  (src < 65536, dst_local < 256)
__global__ __launch_bounds__(256) void bin_write(const int* __restrict__ src,
                                                 const int* __restrict__ dst,
                                                 const float* __restrict__ ew,
                                                 int* cur, uint2* __restrict__ em) {
    __shared__ int h[NB];
    __shared__ int gb[NB];
    for (int i = threadIdx.x; i < NB; i += 256) h[i] = 0;
    __syncthreads();
    int c0 = blockIdx.x * EPB;
    uint2 rec[16];
    int rk[16];
    int bk[16];
#pragma unroll
    for (int j = 0; j < 16; ++j) {
        int e = c0 + j * 256 + threadIdx.x;
        if (e < NE) {
            int dv = dst[e];
            int b = dv >> BN_SH;
            bk[j] = b;
            rk[j] = atomicAdd(&h[b], 1);
            rec[j] = make_uint2((unsigned)src[e] | ((unsigned)(dv & (BNODES - 1)) << 16),
                                __float_as_uint(ew[e]));
        } else bk[j] = -1;
    }
    __syncthreads();
    for (int i = threadIdx.x; i < NB; i += 256) {
        int c = h[i];
        gb[i] = c ? atomicAdd(&cur[i], c) : 0;
    }
    __syncthreads();
#pragma unroll
    for (int j = 0; j < 16; ++j) {
        if (bk[j] >= 0) em[gb[bk[j]] + rk[j]] = rec[j];
    }
}

// K4: per-bucket gather, LDS-accumulated. Block b owns nodes [b*256, b*256+256).
__global__ __launch_bounds__(1024) void bucket_gather(const float* __restrict__ feat,
                                                      const int* __restrict__ base,
                                                      const uint2* __restrict__ em,
                                                      float* __restrict__ agg) {
    __shared__ float a[BNODES * D];   // 64 KB
    int t = threadIdx.x;
    for (int i = t; i < BNODES * D; i += 1024) a[i] = 0.f;
    __syncthreads();
    int b = blockIdx.x;
    int beg = __builtin_amdgcn_readfirstlane(base[b]);
    int end = __builtin_amdgcn_readfirstlane(base[b + 1]);
    int lane = t & 63;
    int w = __builtin_amdgcn_readfirstlane(t >> 6);   // wave id, uniform
#pragma unroll 4
    for (int e = beg + w; e < end; e += 16) {
        uint2 r = em[e];                              // wave-uniform -> scalar load
        unsigned s  = r.x & 0xFFFFu;
        unsigned dl = (r.x >> 16) & 0xFFu;
        float wt = __uint_as_float(r.y);
        float v = feat[(size_t)s * D + lane];
        atomicAdd(&a[dl * D + lane], wt * v);         // ds_add_f32, 2 lanes/bank = free
    }
    __syncthreads();
    int n0 = b << BN_SH;
    for (int rrow = t >> 6; rrow < BNODES; rrow += 16) {
        int n = n0 + rrow;
        if (n < NN) agg[(size_t)n * D + lane] = a[rrow * D + lane];
    }
}

// K5: out[n][d] = bn[d] + sum_k agg[n][k]*Wn[k][d] + sum_k feat[n][k]*Ws[d][k]
__global__ __launch_bounds__(256) void gc_out(const float* __restrict__ feat,
                                              const float* __restrict__ agg,
                                              const float* __restrict__ Wn,
                                              const float* __restrict__ Ws,
                                              const float* __restrict__ bn,
                                              float* __restrict__ out) {
    __shared__ float WB[D * D * 2];   // 32 KB
    for (int i = threadIdx.x; i < D * D; i += 256) {
        int k = i >> 6, d = i & 63;
        WB[2 * i]     = Wn[i];            // Wn[k][d]
        WB[2 * i + 1] = Ws[d * D + k];    // Ws[d][k]
    }
    __syncthreads();
    int d = threadIdx.x & 63;
    float bias = bn[d];
    int wave = blockIdx.x * 4 + (threadIdx.x >> 6);
    int nwave = gridDim.x * 4;
    for (int n0 = wave * 2; n0 < NN; n0 += nwave * 2) {
        int n0u = __builtin_amdgcn_readfirstlane(n0);
        const float* f0 = feat + (size_t)n0u * D;
        const float* a0 = agg + (size_t)n0u * D;
        bool two = (n0u + 1 < NN);
        const float* f1 = f0 + (two ? D : 0);
        const float* a1 = a0 + (two ? D : 0);
        float acc0 = bias, acc1 = bias;
#pragma unroll 8
        for (int k = 0; k < D; ++k) {
            float2 w = *(const float2*)&WB[2 * (k * D + d)];
            acc0 = fmaf(a0[k], w.x, acc0);
            acc0 = fmaf(f0[k], w.y, acc0);
            acc1 = fmaf(a1[k], w.x, acc1);
            acc1 = fmaf(f1[k], w.y, acc1);
        }
        out[(size_t)n0u * D + d] = acc0;
        if (two) out[(size_t)(n0u + 1) * D + d] = acc1;
    }
}

extern "C" void kernel_launch(void* const* d_in, const int* in_sizes, int n_in,
                              void* d_out, int out_size, void* d_ws, size_t ws_size,
                              hipStream_t stream) {
    const float* feat = (const float*)d_in[0];
    const int*   src  = (const int*)d_in[1];
    const int*   dst  = (const int*)d_in[2];
    const float* ew   = (const float*)d_in[3];
    const float* Wn   = (const float*)d_in[4];
    const float* bn   = (const float*)d_in[5];
    const float* Ws   = (const float*)d_in[6];
    float* out = (float*)d_out;

    char* ws = (char*)d_ws;
    float* agg  = (float*)(ws + OFF_AGG);
    uint2* em   = (uint2*)(ws + OFF_EM);
    int*   bc   = (int*)(ws + OFF_BC);
    int*   base = (int*)(ws + OFF_BASE);
    int*   cur  = (int*)(ws + OFF_CUR);

    gc_zero<<<1, 256, 0, stream>>>(bc);
    bin_count<<<256, 256, 0, stream>>>(dst, bc);
    bucket_scan<<<1, 256, 0, stream>>>(bc, base, cur);
    bin_write<<<NWB, 256, 0, stream>>>(src, dst, ew, cur, em);
    bucket_gather<<<NB, 1024, 0, stream>>>(feat, base, em, agg);
    gc_out<<<1024, 256, 0, stream>>>(feat, agg, Wn, Ws, bn, out);
}

// Round 5
// 237.732 us; speedup vs baseline: 1.7851x; 1.7851x over previous
//
#include <hip/hip_runtime.h>

#define NN 50000
#define NE 800000
#define D 64
#define BN_SH 8
#define BNODES 256
#define NB ((NN + BNODES - 1) / BNODES)     // 196 buckets
#define EPB 4096
#define NWB ((NE + EPB - 1) / EPB)          // 196 bin_write blocks

// ---- workspace layout (~13.2 MB) ----
constexpr size_t alignup(size_t x) { return (x + 1023) & ~size_t(1023); }
constexpr size_t OFF_EM   = 0;                                        // NE*8 = 6.4 MB
constexpr size_t OFF_EM2  = alignup(OFF_EM + (size_t)NE * 8);         // NE*8 = 6.4 MB
constexpr size_t OFF_RS   = alignup(OFF_EM2 + (size_t)NE * 8);        // (NN+1) i32
constexpr size_t OFF_BC   = alignup(OFF_RS + (size_t)(NN + 1) * 4);   // NB i32
constexpr size_t OFF_BASE = alignup(OFF_BC + NB * 4);                 // NB+1 i32
constexpr size_t OFF_CUR  = alignup(OFF_BASE + (NB + 1) * 4);         // NB i32

// K0: zero bucket counters
__global__ __launch_bounds__(256) void gc_zero(int* bc) {
    int t = threadIdx.x;
    if (t < NB) bc[t] = 0;
}

// K1: bucket histogram (196 counters, LDS-staged)
__global__ __launch_bounds__(256) void bin_count(const int* __restrict__ dst, int* bc) {
    __shared__ int h[NB];
    for (int i = threadIdx.x; i < NB; i += 256) h[i] = 0;
    __syncthreads();
    for (int e = blockIdx.x * 256 + threadIdx.x; e < NE; e += gridDim.x * 256)
        atomicAdd(&h[dst[e] >> BN_SH], 1);
    __syncthreads();
    for (int i = threadIdx.x; i < NB; i += 256) {
        int c = h[i];
        if (c) atomicAdd(&bc[i], c);
    }
}

// K2: exclusive scan of 196 bucket counts (single block); init cursors; sentinels
__global__ __launch_bounds__(256) void bucket_scan(const int* __restrict__ bc,
                                                   int* base, int* cur, int* rs) {
    __shared__ int sh[256];
    int t = threadIdx.x;
    int v = (t < NB) ? bc[t] : 0;
    sh[t] = v;
    __syncthreads();
    for (int o = 1; o < 256; o <<= 1) {
        int x = (t >= o) ? sh[t - o] : 0;
        __syncthreads();
        sh[t] += x;
        __syncthreads();
    }
    if (t < NB) { int ex = sh[t] - v; base[t] = ex; cur[t] = ex; }
    if (t == 0) { base[NB] = NE; rs[NN] = NE; }
}

// K3: binned edge write, per-block bulk reservation (block-private output runs).
// rec = { src | dst_local<<16 , bits(ew) }  (src < 65536, dst_local < 256)
__global__ __launch_bounds__(256) void bin_write(const int* __restrict__ src,
                                                 const int* __restrict__ dst,
                                                 const float* __restrict__ ew,
                                                 int* cur, uint2* __restrict__ em) {
    __shared__ int h[NB];
    __shared__ int gb[NB];
    for (int i = threadIdx.x; i < NB; i += 256) h[i] = 0;
    __syncthreads();
    int c0 = blockIdx.x * EPB;
    uint2 rec[16];
    int rk[16];
    int bk[16];
#pragma unroll
    for (int j = 0; j < 16; ++j) {
        int e = c0 + j * 256 + threadIdx.x;
        if (e < NE) {
            int dv = dst[e];
            int b = dv >> BN_SH;
            bk[j] = b;
            rk[j] = atomicAdd(&h[b], 1);
            rec[j] = make_uint2((unsigned)src[e] | ((unsigned)(dv & (BNODES - 1)) << 16),
                                __float_as_uint(ew[e]));
        } else bk[j] = -1;
    }
    __syncthreads();
    for (int i = threadIdx.x; i < NB; i += 256) {
        int c = h[i];
        gb[i] = c ? atomicAdd(&cur[i], c) : 0;
    }
    __syncthreads();
#pragma unroll
    for (int j = 0; j < 16; ++j) {
        if (bk[j] >= 0) em[gb[bk[j]] + rk[j]] = rec[j];
    }
}

// K4: per-bucket counting sort -> exact per-node CSR. Two passes over the
// bucket's em run (L2-resident); scatter writes stay inside the block's own
// contiguous window of em2 -> no cross-XCD write amplification.
__global__ __launch_bounds__(256) void bucket_csr(const uint2* __restrict__ em,
                                                  const int* __restrict__ base,
                                                  int* __restrict__ rs,
                                                  uint2* __restrict__ em2) {
    __shared__ int hist[BNODES];
    __shared__ int lbase[BNODES];
    __shared__ int lcur[BNODES];
    __shared__ int sh[BNODES];
    int b = blockIdx.x;
    int t = threadIdx.x;
    int beg = base[b], end = base[b + 1];
    hist[t] = 0;
    __syncthreads();
    for (int e = beg + t; e < end; e += 256)
        atomicAdd(&hist[(em[e].x >> 16) & 0xFFu], 1);
    __syncthreads();
    int v = hist[t];
    sh[t] = v;
    __syncthreads();
    for (int o = 1; o < 256; o <<= 1) {
        int x = (t >= o) ? sh[t - o] : 0;
        __syncthreads();
        sh[t] += x;
        __syncthreads();
    }
    int ex = sh[t] - v;
    lbase[t] = ex;
    lcur[t] = 0;
    int n = (b << BN_SH) + t;
    if (n < NN) rs[n] = beg + ex;
    __syncthreads();
    for (int e = beg + t; e < end; e += 256) {
        uint2 r = em[e];
        unsigned dl = (r.x >> 16) & 0xFFu;
        int pos = beg + lbase[dl] + atomicAdd(&lcur[dl], 1);
        em2[pos] = r;
    }
}

// K5: fused gather + dual matmul + bias. Wave per node (grid-strided):
// lane d accumulates agg[d] over the node's CSR run, then
// out[n][d] = bn[d] + sum_k agg[k]*Wn[k][d] + sum_k feat[n][k]*Ws[d][k]
// via readlane broadcasts against LDS-staged interleaved weights.
__global__ __launch_bounds__(512) void gather_out(const float* __restrict__ feat,
                                                  const int* __restrict__ rs,
                                                  const uint2* __restrict__ em2,
                                                  const float* __restrict__ Wn,
                                                  const float* __restrict__ Ws,
                                                  const float* __restrict__ bn,
                                                  float* __restrict__ out) {
    __shared__ float2 WL[D * D];   // 32 KB: WL[k*64+d] = {Wn[k][d], Ws[d][k]}
    for (int i = threadIdx.x; i < D * D; i += 512) {
        int k = i >> 6, d = i & 63;
        WL[i] = make_float2(Wn[i], Ws[d * D + k]);
    }
    __syncthreads();
    int lane = threadIdx.x & 63;
    float bias = bn[lane];
    int wave = blockIdx.x * 8 + (threadIdx.x >> 6);
    int nwave = gridDim.x * 8;
    for (int n = wave; n < NN; n += nwave) {
        int nu = __builtin_amdgcn_readfirstlane(n);
        int beg = __builtin_amdgcn_readfirstlane(rs[nu]);
        int end = __builtin_amdgcn_readfirstlane(rs[nu + 1]);
        float acc = 0.f;
        for (int e = beg; e < end; ++e) {
            uint2 v = em2[e];
            acc = fmaf(__uint_as_float(v.y),
                       feat[(size_t)(v.x & 0xFFFFu) * D + lane], acc);
        }
        float f = feat[(size_t)nu * D + lane];
        float o = bias;
#pragma unroll
        for (int k = 0; k < D; ++k) {
            float2 w2 = WL[k * D + lane];
            o = fmaf(__shfl(acc, k), w2.x, o);
            o = fmaf(__shfl(f, k), w2.y, o);
        }
        out[(size_t)nu * D + lane] = o;
    }
}

extern "C" void kernel_launch(void* const* d_in, const int* in_sizes, int n_in,
                              void* d_out, int out_size, void* d_ws, size_t ws_size,
                              hipStream_t stream) {
    const float* feat = (const float*)d_in[0];
    const int*   src  = (const int*)d_in[1];
    const int*   dst  = (const int*)d_in[2];
    const float* ew   = (const float*)d_in[3];
    const float* Wn   = (const float*)d_in[4];
    const float* bn   = (const float*)d_in[5];
    const float* Ws   = (const float*)d_in[6];
    float* out = (float*)d_out;

    char* ws = (char*)d_ws;
    uint2* em   = (uint2*)(ws + OFF_EM);
    uint2* em2  = (uint2*)(ws + OFF_EM2);
    int*   rs   = (int*)(ws + OFF_RS);
    int*   bc   = (int*)(ws + OFF_BC);
    int*   base = (int*)(ws + OFF_BASE);
    int*   cur  = (int*)(ws + OFF_CUR);

    gc_zero<<<1, 256, 0, stream>>>(bc);
    bin_count<<<256, 256, 0, stream>>>(dst, bc);
    bucket_scan<<<1, 256, 0, stream>>>(bc, base, cur, rs);
    bin_write<<<NWB, 256, 0, stream>>>(src, dst, ew, cur, em);
    bucket_csr<<<NB, 256, 0, stream>>>(em, base, rs, em2);
    gather_out<<<1024, 512, 0, stream>>>(feat, rs, em2, Wn, Ws, bn, out);
}

// Round 6
// 102.750 us; speedup vs baseline: 4.1301x; 2.3137x over previous
//
#include <hip/hip_runtime.h>

#define NN 50000
#define NE 800000
#define D 64
#define BN_SH 8
#define BNODES 256
#define NB ((NN + BNODES - 1) / BNODES)     // 196 buckets
#define EPB 4096
#define NWB ((NE + EPB - 1) / EPB)          // 196 bin_write blocks

// ---- workspace layout (~26 MB) ----
constexpr size_t alignup(size_t x) { return (x + 1023) & ~size_t(1023); }
constexpr size_t OFF_EM   = 0;                                        // NE*8 = 6.4 MB
constexpr size_t OFF_EM2  = alignup(OFF_EM + (size_t)NE * 8);         // NE*8 = 6.4 MB
constexpr size_t OFF_AGG  = alignup(OFF_EM2 + (size_t)NE * 8);        // NN*D f32 = 12.8 MB
constexpr size_t OFF_RS   = alignup(OFF_AGG + (size_t)NN * D * 4);    // (NN+1) i32
constexpr size_t OFF_BC   = alignup(OFF_RS + (size_t)(NN + 1) * 4);   // NB i32
constexpr size_t OFF_BASE = alignup(OFF_BC + NB * 4);                 // NB+1 i32
constexpr size_t OFF_CUR  = alignup(OFF_BASE + (NB + 1) * 4);         // NB i32

// K0: zero bucket counters
__global__ __launch_bounds__(256) void gc_zero(int* bc) {
    int t = threadIdx.x;
    if (t < NB) bc[t] = 0;
}

// K1: bucket histogram (196 counters, LDS-staged)
__global__ __launch_bounds__(256) void bin_count(const int* __restrict__ dst, int* bc) {
    __shared__ int h[NB];
    for (int i = threadIdx.x; i < NB; i += 256) h[i] = 0;
    __syncthreads();
    for (int e = blockIdx.x * 256 + threadIdx.x; e < NE; e += gridDim.x * 256)
        atomicAdd(&h[dst[e] >> BN_SH], 1);
    __syncthreads();
    for (int i = threadIdx.x; i < NB; i += 256) {
        int c = h[i];
        if (c) atomicAdd(&bc[i], c);
    }
}

// K2: exclusive scan of 196 bucket counts (single block); init cursors; sentinels
__global__ __launch_bounds__(256) void bucket_scan(const int* __restrict__ bc,
                                                   int* base, int* cur, int* rs) {
    __shared__ int sh[256];
    int t = threadIdx.x;
    int v = (t < NB) ? bc[t] : 0;
    sh[t] = v;
    __syncthreads();
    for (int o = 1; o < 256; o <<= 1) {
        int x = (t >= o) ? sh[t - o] : 0;
        __syncthreads();
        sh[t] += x;
        __syncthreads();
    }
    if (t < NB) { int ex = sh[t] - v; base[t] = ex; cur[t] = ex; }
    if (t == 0) { base[NB] = NE; rs[NN] = NE; }
}

// K3: binned edge write, per-block bulk reservation (block-private output runs).
// rec = { src | dst_local<<16 , bits(ew) }  (src < 65536, dst_local < 256)
__global__ __launch_bounds__(256) void bin_write(const int* __restrict__ src,
                                                 const int* __restrict__ dst,
                                                 const float* __restrict__ ew,
                                                 int* cur, uint2* __restrict__ em) {
    __shared__ int h[NB];
    __shared__ int gb[NB];
    for (int i = threadIdx.x; i < NB; i += 256) h[i] = 0;
    __syncthreads();
    int c0 = blockIdx.x * EPB;
    uint2 rec[16];
    int rk[16];
    int bk[16];
#pragma unroll
    for (int j = 0; j < 16; ++j) {
        int e = c0 + j * 256 + threadIdx.x;
        if (e < NE) {
            int dv = dst[e];
            int b = dv >> BN_SH;
            bk[j] = b;
            rk[j] = atomicAdd(&h[b], 1);
            rec[j] = make_uint2((unsigned)src[e] | ((unsigned)(dv & (BNODES - 1)) << 16),
                                __float_as_uint(ew[e]));
        } else bk[j] = -1;
    }
    __syncthreads();
    for (int i = threadIdx.x; i < NB; i += 256) {
        int c = h[i];
        gb[i] = c ? atomicAdd(&cur[i], c) : 0;
    }
    __syncthreads();
#pragma unroll
    for (int j = 0; j < 16; ++j) {
        if (bk[j] >= 0) em[gb[bk[j]] + rk[j]] = rec[j];
    }
}

// K4: per-bucket counting sort -> exact per-node CSR (block-private windows).
__global__ __launch_bounds__(256) void bucket_csr(const uint2* __restrict__ em,
                                                  const int* __restrict__ base,
                                                  int* __restrict__ rs,
                                                  uint2* __restrict__ em2) {
    __shared__ int hist[BNODES];
    __shared__ int lbase[BNODES];
    __shared__ int lcur[BNODES];
    __shared__ int sh[BNODES];
    int b = blockIdx.x;
    int t = threadIdx.x;
    int beg = base[b], end = base[b + 1];
    hist[t] = 0;
    __syncthreads();
    for (int e = beg + t; e < end; e += 256)
        atomicAdd(&hist[(em[e].x >> 16) & 0xFFu], 1);
    __syncthreads();
    int v = hist[t];
    sh[t] = v;
    __syncthreads();
    for (int o = 1; o < 256; o <<= 1) {
        int x = (t >= o) ? sh[t - o] : 0;
        __syncthreads();
        sh[t] += x;
        __syncthreads();
    }
    int ex = sh[t] - v;
    lbase[t] = ex;
    lcur[t] = 0;
    int n = (b << BN_SH) + t;
    if (n < NN) rs[n] = beg + ex;
    __syncthreads();
    for (int e = beg + t; e < end; e += 256) {
        uint2 r = em[e];
        unsigned dl = (r.x >> 16) & 0xFFu;
        int pos = beg + lbase[dl] + atomicAdd(&lcur[dl], 1);
        em2[pos] = r;
    }
}

// K5: gather — wave per node, 4-way unrolled edge loop for memory-level
// parallelism (4 em2 + 4 feat loads in flight). Low VGPR -> full occupancy.
__global__ __launch_bounds__(256) void gc_gather(const float* __restrict__ feat,
                                                 const int* __restrict__ rs,
                                                 const uint2* __restrict__ em2,
                                                 float* __restrict__ agg) {
    int wid = threadIdx.x >> 6;
    int lane = threadIdx.x & 63;
    int n = blockIdx.x * 4 + wid;
    if (n >= NN) return;
    int beg = __builtin_amdgcn_readfirstlane(rs[n]);
    int end = __builtin_amdgcn_readfirstlane(rs[n + 1]);
    float acc = 0.f;
    int e = beg;
    for (; e + 4 <= end; e += 4) {
        uint2 v0 = em2[e], v1 = em2[e + 1], v2 = em2[e + 2], v3 = em2[e + 3];
        float f0 = feat[(size_t)(v0.x & 0xFFFFu) * D + lane];
        float f1 = feat[(size_t)(v1.x & 0xFFFFu) * D + lane];
        float f2 = feat[(size_t)(v2.x & 0xFFFFu) * D + lane];
        float f3 = feat[(size_t)(v3.x & 0xFFFFu) * D + lane];
        acc = fmaf(__uint_as_float(v0.y), f0, acc);
        acc = fmaf(__uint_as_float(v1.y), f1, acc);
        acc = fmaf(__uint_as_float(v2.y), f2, acc);
        acc = fmaf(__uint_as_float(v3.y), f3, acc);
    }
    for (; e < end; ++e) {
        uint2 v = em2[e];
        acc = fmaf(__uint_as_float(v.y), feat[(size_t)(v.x & 0xFFFFu) * D + lane], acc);
    }
    agg[(size_t)n * D + lane] = acc;
}

// K6: epilogue as GEMM: C[N,64] = [agg | feat] @ [Wn ; Ws^T] + bn.
// Block = 128 rows; B (128x64, 32 KB) staged once; A staged in 32-k chunks
// (stride 36 -> conflict-free float4 reads with rows stepped by 32).
// Thread tile: 4 rows x 8 cols in registers -> W reused across 128 nodes.
#define BM 128
__global__ __launch_bounds__(256) void gemm_out(const float* __restrict__ agg,
                                                const float* __restrict__ feat,
                                                const float* __restrict__ Wn,
                                                const float* __restrict__ Ws,
                                                const float* __restrict__ bn,
                                                float* __restrict__ out) {
    __shared__ float Bs[128 * 64];   // 32 KB: Bs[k*64+d]
    __shared__ float As[BM * 36];    // 18 KB, stride 36
    int tid = threadIdx.x;
    for (int i = tid; i < 128 * 64; i += 256) {
        int k = i >> 6, d = i & 63;
        Bs[i] = (k < 64) ? Wn[i] : Ws[d * 64 + (k - 64)];
    }
    int tn = tid & 7;        // col group: cols tn*8 .. +7
    int tm = tid >> 3;       // 0..31: rows tm + 32*i
    float4 blo = *(const float4*)&bn[tn * 8];
    float4 bhi = *(const float4*)&bn[tn * 8 + 4];
    float acc[4][8];
#pragma unroll
    for (int i = 0; i < 4; ++i) {
        acc[i][0] = blo.x; acc[i][1] = blo.y; acc[i][2] = blo.z; acc[i][3] = blo.w;
        acc[i][4] = bhi.x; acc[i][5] = bhi.y; acc[i][6] = bhi.z; acc[i][7] = bhi.w;
    }
    int n0 = blockIdx.x * BM;
    for (int c = 0; c < 4; ++c) {
        const float* Asrc = (c < 2) ? agg : feat;
        int ksrc = (c & 1) * 32;
        __syncthreads();
        // stage A chunk: rows n0..n0+127, cols ksrc..ksrc+31
        for (int i = tid; i < BM * 8; i += 256) {
            int r = i >> 3, c4 = i & 7;
            int nrow = n0 + r;
            const float* p = Asrc + (size_t)(nrow < NN ? nrow : 0) * 64 + ksrc + c4 * 4;
            float4 v = *(const float4*)p;
            float* q = &As[r * 36 + c4 * 4];
            q[0] = v.x; q[1] = v.y; q[2] = v.z; q[3] = v.w;
        }
        __syncthreads();
        int kb = c * 32;
#pragma unroll
        for (int k4 = 0; k4 < 8; ++k4) {
            float4 av[4];
#pragma unroll
            for (int i = 0; i < 4; ++i)
                av[i] = *(const float4*)&As[(tm + 32 * i) * 36 + k4 * 4];
#pragma unroll
            for (int kk = 0; kk < 4; ++kk) {
                int k = kb + k4 * 4 + kk;
                float4 wlo = *(const float4*)&Bs[k * 64 + tn * 8];
                float4 whi = *(const float4*)&Bs[k * 64 + tn * 8 + 4];
#pragma unroll
                for (int i = 0; i < 4; ++i) {
                    float a = (kk == 0) ? av[i].x : (kk == 1) ? av[i].y
                            : (kk == 2) ? av[i].z : av[i].w;
                    acc[i][0] = fmaf(a, wlo.x, acc[i][0]);
                    acc[i][1] = fmaf(a, wlo.y, acc[i][1]);
                    acc[i][2] = fmaf(a, wlo.z, acc[i][2]);
                    acc[i][3] = fmaf(a, wlo.w, acc[i][3]);
                    acc[i][4] = fmaf(a, whi.x, acc[i][4]);
                    acc[i][5] = fmaf(a, whi.y, acc[i][5]);
                    acc[i][6] = fmaf(a, whi.z, acc[i][6]);
                    acc[i][7] = fmaf(a, whi.w, acc[i][7]);
                }
            }
        }
    }
#pragma unroll
    for (int i = 0; i < 4; ++i) {
        int r = n0 + tm + 32 * i;
        if (r < NN) {
            float* p = &out[(size_t)r * 64 + tn * 8];
            *(float4*)p = make_float4(acc[i][0], acc[i][1], acc[i][2], acc[i][3]);
            *(float4*)(p + 4) = make_float4(acc[i][4], acc[i][5], acc[i][6], acc[i][7]);
        }
    }
}

extern "C" void kernel_launch(void* const* d_in, const int* in_sizes, int n_in,
                              void* d_out, int out_size, void* d_ws, size_t ws_size,
                              hipStream_t stream) {
    const float* feat = (const float*)d_in[0];
    const int*   src  = (const int*)d_in[1];
    const int*   dst  = (const int*)d_in[2];
    const float* ew   = (const float*)d_in[3];
    const float* Wn   = (const float*)d_in[4];
    const float* bn   = (const float*)d_in[5];
    const float* Ws   = (const float*)d_in[6];
    float* out = (float*)d_out;

    char* ws = (char*)d_ws;
    uint2* em   = (uint2*)(ws + OFF_EM);
    uint2* em2  = (uint2*)(ws + OFF_EM2);
    float* agg  = (float*)(ws + OFF_AGG);
    int*   rs   = (int*)(ws + OFF_RS);
    int*   bc   = (int*)(ws + OFF_BC);
    int*   base = (int*)(ws + OFF_BASE);
    int*   cur  = (int*)(ws + OFF_CUR);

    gc_zero<<<1, 256, 0, stream>>>(bc);
    bin_count<<<256, 256, 0, stream>>>(dst, bc);
    bucket_scan<<<1, 256, 0, stream>>>(bc, base, cur, rs);
    bin_write<<<NWB, 256, 0, stream>>>(src, dst, ew, cur, em);
    bucket_csr<<<NB, 256, 0, stream>>>(em, base, rs, em2);
    gc_gather<<<(NN + 3) / 4, 256, 0, stream>>>(feat, rs, em2, agg);
    gemm_out<<<(NN + BM - 1) / BM, 256, 0, stream>>>(agg, feat, Wn, Ws, bn, out);
}

// Round 8
// 98.095 us; speedup vs baseline: 4.3261x; 1.0475x over previous
//
#include <hip/hip_runtime.h>

#define NN 50000
#define NE 800000
#define D 64
#define BN_SH 8
#define BNODES 256
#define NB ((NN + BNODES - 1) / BNODES)     // 196 buckets
#define EPB 4096
#define NWB ((NE + EPB - 1) / EPB)          // 196 edge-chunk blocks
#define CONV_B 800                          // feat->bf16 convert blocks

// ---- workspace layout (~29 MB) ----
constexpr size_t alignup(size_t x) { return (x + 1023) & ~size_t(1023); }
constexpr size_t OFF_EM   = 0;                                        // NE*8   = 6.4 MB
constexpr size_t OFF_EM2  = alignup(OFF_EM + (size_t)NE * 8);         // NE*4   = 3.2 MB
constexpr size_t OFF_AGG  = alignup(OFF_EM2 + (size_t)NE * 4);        // NN*D*4 = 12.8 MB
constexpr size_t OFF_FB   = alignup(OFF_AGG + (size_t)NN * D * 4);    // NN*D*2 = 6.4 MB
constexpr size_t OFF_RS   = alignup(OFF_FB + (size_t)NN * D * 2);     // (NN+1) i32
constexpr size_t OFF_CNT  = alignup(OFF_RS + (size_t)(NN + 1) * 4);   // NWB*NB i32 = 154 KB
constexpr size_t OFF_BASE = alignup(OFF_CNT + (size_t)NWB * NB * 4);  // NB+1 i32

__device__ __forceinline__ unsigned f2bf(unsigned u) {   // f32 bits -> bf16 bits, RNE
    return (u + 0x7FFFu + ((u >> 16) & 1u)) >> 16;
}

// K1: blocks [0,NWB): per-chunk bucket histogram -> cnt[blk][b] (deterministic,
//     row-private writes). blocks [NWB, NWB+CONV_B): feat -> bf16 convert.
__global__ __launch_bounds__(256) void prep(const int* __restrict__ dst,
                                            const float* __restrict__ feat,
                                            int* __restrict__ cnt,
                                            ushort* __restrict__ fb16) {
    int b = blockIdx.x;
    if (b < NWB) {
        __shared__ int h[NB];
        for (int i = threadIdx.x; i < NB; i += 256) h[i] = 0;
        __syncthreads();
        int c0 = b * EPB;
        int lim = min(EPB, NE - c0);
        for (int j = threadIdx.x; j < lim; j += 256)
            atomicAdd(&h[dst[c0 + j] >> BN_SH], 1);
        __syncthreads();
        for (int i = threadIdx.x; i < NB; i += 256) cnt[b * NB + i] = h[i];
    } else {
        int cb = b - NWB;
        const float4* f4 = (const float4*)feat;
        ushort4* o4 = (ushort4*)fb16;
        for (int i = cb * 256 + threadIdx.x; i < NN * D / 4; i += CONV_B * 256) {
            float4 v = f4[i];
            ushort4 o;
            o.x = (ushort)f2bf(__float_as_uint(v.x));
            o.y = (ushort)f2bf(__float_as_uint(v.y));
            o.z = (ushort)f2bf(__float_as_uint(v.z));
            o.w = (ushort)f2bf(__float_as_uint(v.w));
            o4[i] = o;
        }
    }
}

// K2: single block. Bucket totals from cnt columns -> exclusive bases; then
// rewrite cnt[blk][b] in-place as the per-(block,bucket) write base.
__global__ __launch_bounds__(256) void scanw(int* __restrict__ cnt,
                                             int* __restrict__ base,
                                             int* __restrict__ rs) {
    __shared__ int sh[256];
    int t = threadIdx.x;
    int total = 0;
    if (t < NB)
        for (int blk = 0; blk < NWB; ++blk) total += cnt[blk * NB + t];
    sh[t] = total;
    __syncthreads();
    for (int o = 1; o < 256; o <<= 1) {
        int x = (t >= o) ? sh[t - o] : 0;
        __syncthreads();
        sh[t] += x;
        __syncthreads();
    }
    int ex = sh[t] - total;
    if (t < NB) {
        base[t] = ex;
        int run = ex;
        for (int blk = 0; blk < NWB; ++blk) {
            int v = cnt[blk * NB + t];
            cnt[blk * NB + t] = run;
            run += v;
        }
    }
    if (t == 0) { base[NB] = NE; rs[NN] = NE; }
}

// K3: binned edge write, fully deterministic (bases precomputed, ranks via LDS).
// rec = { src | dst_local<<16 , bits(ew) }
__global__ __launch_bounds__(256) void bin_write(const int* __restrict__ src,
                                                 const int* __restrict__ dst,
                                                 const float* __restrict__ ew,
                                                 const int* __restrict__ cnt,
                                                 uint2* __restrict__ em) {
    __shared__ int h[NB];
    __shared__ int gb[NB];
    for (int i = threadIdx.x; i < NB; i += 256) h[i] = 0;
    __syncthreads();
    int c0 = blockIdx.x * EPB;
    uint2 rec[16];
    int rk[16];
    int bk[16];
#pragma unroll
    for (int j = 0; j < 16; ++j) {
        int e = c0 + j * 256 + threadIdx.x;
        if (e < NE) {
            int dv = dst[e];
            int b = dv >> BN_SH;
            bk[j] = b;
            rk[j] = atomicAdd(&h[b], 1);
            rec[j] = make_uint2((unsigned)src[e] | ((unsigned)(dv & (BNODES - 1)) << 16),
                                __float_as_uint(ew[e]));
        } else bk[j] = -1;
    }
    __syncthreads();
    for (int i = threadIdx.x; i < NB; i += 256) gb[i] = cnt[blockIdx.x * NB + i];
    __syncthreads();
#pragma unroll
    for (int j = 0; j < 16; ++j)
        if (bk[j] >= 0) em[gb[bk[j]] + rk[j]] = rec[j];
}

// K4: per-bucket counting sort -> exact per-node CSR; em2 packed to 4 B:
// { src:16 | bf16(w):16 }  (dst_local no longer needed after the sort).
__global__ __launch_bounds__(256) void bucket_csr(const uint2* __restrict__ em,
                                                  const int* __restrict__ base,
                                                  int* __restrict__ rs,
                                                  unsigned* __restrict__ em2) {
    __shared__ int hist[BNODES];
    __shared__ int lbase[BNODES];
    __shared__ int lcur[BNODES];
    __shared__ int sh[BNODES];
    int b = blockIdx.x;
    int t = threadIdx.x;
    int beg = base[b], end = base[b + 1];
    hist[t] = 0;
    __syncthreads();
    for (int e = beg + t; e < end; e += 256)
        atomicAdd(&hist[(em[e].x >> 16) & 0xFFu], 1);
    __syncthreads();
    int v = hist[t];
    sh[t] = v;
    __syncthreads();
    for (int o = 1; o < 256; o <<= 1) {
        int x = (t >= o) ? sh[t - o] : 0;
        __syncthreads();
        sh[t] += x;
        __syncthreads();
    }
    int ex = sh[t] - v;
    lbase[t] = ex;
    lcur[t] = 0;
    int n = (b << BN_SH) + t;
    if (n < NN) rs[n] = beg + ex;
    __syncthreads();
    for (int e = beg + t; e < end; e += 256) {
        uint2 r = em[e];
        unsigned dl = (r.x >> 16) & 0xFFu;
        int pos = beg + lbase[dl] + atomicAdd(&lcur[dl], 1);
        em2[pos] = (r.x & 0xFFFFu) | (f2bf(r.y) << 16);
    }
}

// K5: gather — wave per node, bf16 feat rows (128 B), 4-way unrolled for MLP.
__global__ __launch_bounds__(256) void gc_gather(const ushort* __restrict__ fb16,
                                                 const int* __restrict__ rs,
                                                 const unsigned* __restrict__ em2,
                                                 float* __restrict__ agg) {
    int wid = threadIdx.x >> 6;
    int lane = threadIdx.x & 63;
    int n = blockIdx.x * 4 + wid;
    if (n >= NN) return;
    int beg = __builtin_amdgcn_readfirstlane(rs[n]);
    int end = __builtin_amdgcn_readfirstlane(rs[n + 1]);
    float acc = 0.f;
    int e = beg;
    for (; e + 4 <= end; e += 4) {
        unsigned v0 = em2[e], v1 = em2[e + 1], v2 = em2[e + 2], v3 = em2[e + 3];
        float f0 = __uint_as_float((unsigned)fb16[(size_t)(v0 & 0xFFFFu) * D + lane] << 16);
        float f1 = __uint_as_float((unsigned)fb16[(size_t)(v1 & 0xFFFFu) * D + lane] << 16);
        float f2 = __uint_as_float((unsigned)fb16[(size_t)(v2 & 0xFFFFu) * D + lane] << 16);
        float f3 = __uint_as_float((unsigned)fb16[(size_t)(v3 & 0xFFFFu) * D + lane] << 16);
        acc = fmaf(__uint_as_float(v0 & 0xFFFF0000u), f0, acc);
        acc = fmaf(__uint_as_float(v1 & 0xFFFF0000u), f1, acc);
        acc = fmaf(__uint_as_float(v2 & 0xFFFF0000u), f2, acc);
        acc = fmaf(__uint_as_float(v3 & 0xFFFF0000u), f3, acc);
    }
    for (; e < end; ++e) {
        unsigned v = em2[e];
        float f = __uint_as_float((unsigned)fb16[(size_t)(v & 0xFFFFu) * D + lane] << 16);
        acc = fmaf(__uint_as_float(v & 0xFFFF0000u), f, acc);
    }
    agg[(size_t)n * D + lane] = acc;
}

// K6: epilogue GEMM: C[N,64] = [agg | feat] @ [Wn ; Ws^T] + bn.
#define BM 128
__global__ __launch_bounds__(256) void gemm_out(const float* __restrict__ agg,
                                                const float* __restrict__ feat,
                                                const float* __restrict__ Wn,
                                                const float* __restrict__ Ws,
                                                const float* __restrict__ bn,
                                                float* __restrict__ out) {
    __shared__ float Bs[128 * 64];   // 32 KB: Bs[k*64+d]
    __shared__ float As[BM * 36];    // 18 KB, stride 36
    int tid = threadIdx.x;
    for (int i = tid; i < 128 * 64; i += 256) {
        int k = i >> 6, d = i & 63;
        Bs[i] = (k < 64) ? Wn[i] : Ws[d * 64 + (k - 64)];
    }
    int tn = tid & 7;
    int tm = tid >> 3;
    float4 blo = *(const float4*)&bn[tn * 8];
    float4 bhi = *(const float4*)&bn[tn * 8 + 4];
    float acc[4][8];
#pragma unroll
    for (int i = 0; i < 4; ++i) {
        acc[i][0] = blo.x; acc[i][1] = blo.y; acc[i][2] = blo.z; acc[i][3] = blo.w;
        acc[i][4] = bhi.x; acc[i][5] = bhi.y; acc[i][6] = bhi.z; acc[i][7] = bhi.w;
    }
    int n0 = blockIdx.x * BM;
    for (int c = 0; c < 4; ++c) {
        const float* Asrc = (c < 2) ? agg : feat;
        int ksrc = (c & 1) * 32;
        __syncthreads();
        for (int i = tid; i < BM * 8; i += 256) {
            int r = i >> 3, c4 = i & 7;
            int nrow = n0 + r;
            const float* p = Asrc + (size_t)(nrow < NN ? nrow : 0) * 64 + ksrc + c4 * 4;
            float4 v = *(const float4*)p;
            float* q = &As[r * 36 + c4 * 4];
            q[0] = v.x; q[1] = v.y; q[2] = v.z; q[3] = v.w;
        }
        __syncthreads();
        int kb = c * 32;
#pragma unroll
        for (int k4 = 0; k4 < 8; ++k4) {
            float4 av[4];
#pragma unroll
            for (int i = 0; i < 4; ++i)
                av[i] = *(const float4*)&As[(tm + 32 * i) * 36 + k4 * 4];
#pragma unroll
            for (int kk = 0; kk < 4; ++kk) {
                int k = kb + k4 * 4 + kk;
                float4 wlo = *(const float4*)&Bs[k * 64 + tn * 8];
                float4 whi = *(const float4*)&Bs[k * 64 + tn * 8 + 4];
#pragma unroll
                for (int i = 0; i < 4; ++i) {
                    float a = (kk == 0) ? av[i].x : (kk == 1) ? av[i].y
                            : (kk == 2) ? av[i].z : av[i].w;
                    acc[i][0] = fmaf(a, wlo.x, acc[i][0]);
                    acc[i][1] = fmaf(a, wlo.y, acc[i][1]);
                    acc[i][2] = fmaf(a, wlo.z, acc[i][2]);
                    acc[i][3] = fmaf(a, wlo.w, acc[i][3]);
                    acc[i][4] = fmaf(a, whi.x, acc[i][4]);
                    acc[i][5] = fmaf(a, whi.y, acc[i][5]);
                    acc[i][6] = fmaf(a, whi.z, acc[i][6]);
                    acc[i][7] = fmaf(a, whi.w, acc[i][7]);
                }
            }
        }
    }
#pragma unroll
    for (int i = 0; i < 4; ++i) {
        int r = n0 + tm + 32 * i;
        if (r < NN) {
            float* p = &out[(size_t)r * 64 + tn * 8];
            *(float4*)p = make_float4(acc[i][0], acc[i][1], acc[i][2], acc[i][3]);
            *(float4*)(p + 4) = make_float4(acc[i][4], acc[i][5], acc[i][6], acc[i][7]);
        }
    }
}

extern "C" void kernel_launch(void* const* d_in, const int* in_sizes, int n_in,
                              void* d_out, int out_size, void* d_ws, size_t ws_size,
                              hipStream_t stream) {
    const float* feat = (const float*)d_in[0];
    const int*   src  = (const int*)d_in[1];
    const int*   dst  = (const int*)d_in[2];
    const float* ew   = (const float*)d_in[3];
    const float* Wn   = (const float*)d_in[4];
    const float* bn   = (const float*)d_in[5];
    const float* Ws   = (const float*)d_in[6];
    float* out = (float*)d_out;

    char* ws = (char*)d_ws;
    uint2*    em   = (uint2*)(ws + OFF_EM);
    unsigned* em2  = (unsigned*)(ws + OFF_EM2);
    float*    agg  = (float*)(ws + OFF_AGG);
    ushort*   fb16 = (ushort*)(ws + OFF_FB);
    int*      rs   = (int*)(ws + OFF_RS);
    int*      cnt  = (int*)(ws + OFF_CNT);
    int*      base = (int*)(ws + OFF_BASE);

    prep<<<NWB + CONV_B, 256, 0, stream>>>(dst, feat, cnt, fb16);
    scanw<<<1, 256, 0, stream>>>(cnt, base, rs);
    bin_write<<<NWB, 256, 0, stream>>>(src, dst, ew, cnt, em);
    bucket_csr<<<NB, 256, 0, stream>>>(em, base, rs, em2);
    gc_gather<<<(NN + 3) / 4, 256, 0, stream>>>(fb16, rs, em2, agg);
    gemm_out<<<(NN + BM - 1) / BM, 256, 0, stream>>>(agg, feat, Wn, Ws, bn, out);
}